// Round 6
// baseline (309.597 us; speedup 1.0000x reference)
//
#include <hip/hip_runtime.h>
#include <hip/hip_bf16.h>

#define N_NODES 50000
#define N_EDGES 600000
#define DIM 128
#define GROUPS 32
#define EPS 1e-5f

#define NPB 64              // nodes per block in GEMM
#define SCAN_CHUNK 1024     // counts per block in scan passes
#define SCAN_NB ((N_NODES + SCAN_CHUNK - 1) / SCAN_CHUNK)   // 49

// s[n][d] = t*W[0][d] + b[d] + sum_k xin[n][k] * W[k+1][d]
__global__ __launch_bounds__(256) void gemm_kernel(
    const float* __restrict__ xin, const float* __restrict__ W,
    const float* __restrict__ bias, const float* __restrict__ tptr,
    float* __restrict__ out, int N)
{
    __shared__ float xs[NPB][DIM];     // 32 KB
    const int tid = threadIdx.x;
    const int nb = blockIdx.x * NPB;

    // stage x tile: 64 nodes * 32 float4 = 2048 float4, 8 per thread
    const float4* xin4 = (const float4*)xin;
#pragma unroll
    for (int i = 0; i < 8; ++i) {
        int f4 = tid + i * 256;            // 0..2047
        int nl = f4 >> 5;                  // local node
        int q  = f4 & 31;                  // float4 within node
        int node = nb + nl;
        float4 v = make_float4(0.f, 0.f, 0.f, 0.f);
        if (node < N) v = xin4[(size_t)node * 32 + q];
        *(float4*)&xs[nl][q * 4] = v;
    }
    __syncthreads();

    const int dq   = (tid & 31) * 4;       // dim quad base 0..124
    const int nloc = (tid >> 5) * 8;       // node base in tile 0..56

    float4 acc[8];
#pragma unroll
    for (int i = 0; i < 8; ++i) acc[i] = make_float4(0.f, 0.f, 0.f, 0.f);

    for (int k = 0; k < DIM; k += 4) {
        float4 w0 = *(const float4*)&W[(k + 1) * DIM + dq];
        float4 w1 = *(const float4*)&W[(k + 2) * DIM + dq];
        float4 w2 = *(const float4*)&W[(k + 3) * DIM + dq];
        float4 w3 = *(const float4*)&W[(k + 4) * DIM + dq];
#pragma unroll
        for (int i = 0; i < 8; ++i) {
            float4 xv = *(const float4*)&xs[nloc + i][k];
            acc[i].x = fmaf(xv.x, w0.x, fmaf(xv.y, w1.x, fmaf(xv.z, w2.x, fmaf(xv.w, w3.x, acc[i].x))));
            acc[i].y = fmaf(xv.x, w0.y, fmaf(xv.y, w1.y, fmaf(xv.z, w2.y, fmaf(xv.w, w3.y, acc[i].y))));
            acc[i].z = fmaf(xv.x, w0.z, fmaf(xv.y, w1.z, fmaf(xv.z, w2.z, fmaf(xv.w, w3.z, acc[i].z))));
            acc[i].w = fmaf(xv.x, w0.w, fmaf(xv.y, w1.w, fmaf(xv.z, w2.w, fmaf(xv.w, w3.w, acc[i].w))));
        }
    }

    const float tval = *tptr;
    float4 w0r = *(const float4*)&W[dq];        // t-row (row 0 of W)
    float4 bb  = *(const float4*)&bias[dq];
#pragma unroll
    for (int i = 0; i < 8; ++i) {
        int node = nb + nloc + i;
        if (node < N) {
            float4 r;
            r.x = acc[i].x + tval * w0r.x + bb.x;
            r.y = acc[i].y + tval * w0r.y + bb.y;
            r.z = acc[i].z + tval * w0r.z + bb.z;
            r.w = acc[i].w + tval * w0r.w + bb.w;
            *(float4*)&out[(size_t)node * DIM + dq] = r;
        }
    }
}

// ---- CSR build ----
__global__ __launch_bounds__(256) void hist_kernel(
    const int* __restrict__ tgt, int* __restrict__ counts, int E)
{
    int e = blockIdx.x * 256 + threadIdx.x;
    if (e < E) atomicAdd(&counts[tgt[e]], 1);
}

// pass 1: bsum[b] = sum of counts[b*1024 .. b*1024+1023]
__global__ __launch_bounds__(256) void scan_pass1(
    const int* __restrict__ counts, int* __restrict__ bsum, int N)
{
    __shared__ int sh[256];
    const int tid = threadIdx.x;
    const int n4 = N / 4;
    int idx4 = blockIdx.x * 256 + tid;
    int4 c = make_int4(0, 0, 0, 0);
    if (idx4 < n4) c = ((const int4*)counts)[idx4];
    sh[tid] = c.x + c.y + c.z + c.w;
    __syncthreads();
#pragma unroll
    for (int off = 128; off > 0; off >>= 1) {
        if (tid < off) sh[tid] += sh[tid + off];
        __syncthreads();
    }
    if (tid == 0) bsum[blockIdx.x] = sh[0];
}

// pass 2: exclusive scan of bsum[0..nb) in one wave (nb <= 64)
__global__ __launch_bounds__(64) void scan_bsum(int* __restrict__ bsum, int nb)
{
    int lane = threadIdx.x;
    int v = (lane < nb) ? bsum[lane] : 0;
    int incl = v;
#pragma unroll
    for (int off = 1; off < 64; off <<= 1) {
        int u = __shfl_up(incl, off);
        if (lane >= off) incl += u;
    }
    if (lane < nb) bsum[lane] = incl - v;      // exclusive
}

// pass 3: rowptr = exclusive scan of counts, using bsum offsets; also rowptr[N]
__global__ __launch_bounds__(256) void scan_pass3(
    const int* __restrict__ counts, const int* __restrict__ bsum,
    int* __restrict__ rowptr, int N)
{
    __shared__ int sh[256];
    const int tid = threadIdx.x;
    const int n4 = N / 4;
    int idx4 = blockIdx.x * 256 + tid;
    int4 c = make_int4(0, 0, 0, 0);
    if (idx4 < n4) c = ((const int4*)counts)[idx4];
    int tsum = c.x + c.y + c.z + c.w;
    sh[tid] = tsum;
    __syncthreads();
#pragma unroll
    for (int off = 1; off < 256; off <<= 1) {
        int v = (tid >= off) ? sh[tid - off] : 0;
        __syncthreads();
        sh[tid] += v;
        __syncthreads();
    }
    int base = bsum[blockIdx.x] + sh[tid] - tsum;   // exclusive prefix for my 4
    if (idx4 < n4) {
        int4 r;
        r.x = base;
        r.y = base + c.x;
        r.z = r.y + c.y;
        r.w = r.z + c.z;
        ((int4*)rowptr)[idx4] = r;
        if (idx4 == n4 - 1) rowptr[N] = r.w + c.w;
    }
}

// eid[pos] = src, bucketed by tgt. cursor holds counts on entry, 0 on exit.
__global__ __launch_bounds__(256) void place_kernel(
    const int* __restrict__ src, const int* __restrict__ tgt,
    const int* __restrict__ rowptr,
    int* __restrict__ cursor, int* __restrict__ eid, int E)
{
    int e = blockIdx.x * 256 + threadIdx.x;
    if (e >= E) return;
    int t = tgt[e];
    int idx = atomicSub(&cursor[t], 1) - 1;    // slot within row
    eid[rowptr[t] + idx] = src[e];
}

// One 64-lane wave per node: half = lane>>5 picks edge parity, quad = lane&31
// picks the float4 of the row. 4 edges per half in flight per iteration.
__global__ __launch_bounds__(256) void gather_gn_kernel(
    const float4* __restrict__ s4, const int* __restrict__ rowptr,
    const int* __restrict__ eid,
    const float* __restrict__ gamma, const float* __restrict__ beta,
    float* __restrict__ out, int N)
{
    int node = blockIdx.x * 4 + (threadIdx.x >> 6);
    if (node >= N) return;
    int lane = threadIdx.x & 63;
    int half = lane >> 5;
    int quad = lane & 31;

    int beg = rowptr[node];
    int end = rowptr[node + 1];

    float4 acc = make_float4(0.f, 0.f, 0.f, 0.f);
    int j = beg + half;
    // 8 edges per wave iteration = 4 per half (stride 2 within half)
    for (; j + 6 < end; j += 8) {
        int i0 = eid[j];
        int i1 = eid[j + 2];
        int i2 = eid[j + 4];
        int i3 = eid[j + 6];
        float4 v0 = s4[(size_t)i0 * 32 + quad];
        float4 v1 = s4[(size_t)i1 * 32 + quad];
        float4 v2 = s4[(size_t)i2 * 32 + quad];
        float4 v3 = s4[(size_t)i3 * 32 + quad];
        acc.x += (v0.x + v1.x) + (v2.x + v3.x);
        acc.y += (v0.y + v1.y) + (v2.y + v3.y);
        acc.z += (v0.z + v1.z) + (v2.z + v3.z);
        acc.w += (v0.w + v1.w) + (v2.w + v3.w);
    }
    for (; j < end; j += 2) {
        float4 v0 = s4[(size_t)eid[j] * 32 + quad];
        acc.x += v0.x;
        acc.y += v0.y;
        acc.z += v0.z;
        acc.w += v0.w;
    }

    // combine the two halves: lane q gets half0[q] + half1[q]
    acc.x += __shfl_xor(acc.x, 32);
    acc.y += __shfl_xor(acc.y, 32);
    acc.z += __shfl_xor(acc.z, 32);
    acc.w += __shfl_xor(acc.w, 32);

    if (half == 0) {
        int deg = end - beg;
        float inv = (deg > 0) ? (1.0f / (float)deg) : 0.0f;
        acc.x = fmaxf(acc.x * inv, 0.f);
        acc.y = fmaxf(acc.y * inv, 0.f);
        acc.z = fmaxf(acc.z * inv, 0.f);
        acc.w = fmaxf(acc.w * inv, 0.f);

        float mu = 0.25f * (acc.x + acc.y + acc.z + acc.w);
        float dx = acc.x - mu, dy = acc.y - mu, dz = acc.z - mu, dw = acc.w - mu;
        float var = 0.25f * (dx * dx + dy * dy + dz * dz + dw * dw);
        float rs = rsqrtf(var + EPS);
        float4 gm = *(const float4*)&gamma[quad * 4];
        float4 bt = *(const float4*)&beta[quad * 4];
        float4 r;
        r.x = dx * rs * gm.x + bt.x;
        r.y = dy * rs * gm.y + bt.y;
        r.z = dz * rs * gm.z + bt.z;
        r.w = dw * rs * gm.w + bt.w;
        *(float4*)&out[(size_t)node * DIM + quad * 4] = r;
    }
}

extern "C" void kernel_launch(void* const* d_in, const int* in_sizes, int n_in,
                              void* d_out, int out_size, void* d_ws, size_t ws_size,
                              hipStream_t stream) {
    const float* t      = (const float*)d_in[0];
    const float* x      = (const float*)d_in[1];
    const int*   src    = (const int*)d_in[2];
    const int*   tgt    = (const int*)d_in[3];
    const float* W1     = (const float*)d_in[5];
    const float* b1     = (const float*)d_in[6];
    const float* W2     = (const float*)d_in[7];
    const float* b2     = (const float*)d_in[8];
    const float* gamma1 = (const float*)d_in[9];
    const float* beta1  = (const float*)d_in[10];
    const float* gamma2 = (const float*)d_in[11];
    const float* beta2  = (const float*)d_in[12];
    float* out = (float*)d_out;

    const size_t NODE_BYTES = (size_t)N_NODES * DIM * sizeof(float);  // 25.6 MB
    char* ws = (char*)d_ws;
    size_t off = 0;
    float* s_buf  = (float*)(ws + off); off += NODE_BYTES;                 // 25.6 MB
    int*   rowptr = (int*)(ws + off);   off += ((size_t)N_NODES + 4) * 4;
    off = (off + 255) & ~(size_t)255;
    int*   cursor = (int*)(ws + off);   off += (size_t)N_NODES * 4;
    off = (off + 255) & ~(size_t)255;
    int*   bsum   = (int*)(ws + off);   off += 64 * 4;
    off = (off + 255) & ~(size_t)255;
    int*   eid    = (int*)(ws + off);   off += (size_t)N_EDGES * 4;        // 2.4 MB

    const int gemm_grid   = (N_NODES + NPB - 1) / NPB;     // 782
    const int edge_grid   = (N_EDGES + 255) / 256;         // 2344
    const int gather_grid = (N_NODES + 3) / 4;             // 12500

    // ---- CSR build (shared by both layers) ----
    hipMemsetAsync(cursor, 0, (size_t)N_NODES * 4, stream);
    hist_kernel<<<edge_grid, 256, 0, stream>>>(tgt, cursor, N_EDGES);      // cursor = counts
    scan_pass1<<<SCAN_NB, 256, 0, stream>>>(cursor, bsum, N_NODES);
    scan_bsum<<<1, 64, 0, stream>>>(bsum, SCAN_NB);
    scan_pass3<<<SCAN_NB, 256, 0, stream>>>(cursor, bsum, rowptr, N_NODES);
    place_kernel<<<edge_grid, 256, 0, stream>>>(src, tgt, rowptr, cursor, eid, N_EDGES);

    // ---- layer 1 ----  (h lives in d_out; gemm2 consumes it before gather2 overwrites)
    gemm_kernel<<<gemm_grid, 256, 0, stream>>>(x, W1, b1, t, s_buf, N_NODES);
    gather_gn_kernel<<<gather_grid, 256, 0, stream>>>((const float4*)s_buf, rowptr, eid, gamma1, beta1, out, N_NODES);

    // ---- layer 2 ----
    gemm_kernel<<<gemm_grid, 256, 0, stream>>>(out, W2, b2, t, s_buf, N_NODES);
    gather_gn_kernel<<<gather_grid, 256, 0, stream>>>((const float4*)s_buf, rowptr, eid, gamma2, beta2, out, N_NODES);
}